// Round 2
// baseline (669.566 us; speedup 1.0000x reference)
//
#include <hip/hip_runtime.h>
#include <math.h>

#define S_DIM 128
#define R_DIM 256
#define CM_DIM 256
#define CZ_DIM 128
#define C_DIM 32
#define H_DIM 8
#define HC_DIM 256
#define LN_EPS 1e-5f

__device__ __forceinline__ float wave_sum(float v) {
#pragma unroll
    for (int off = 32; off > 0; off >>= 1) v += __shfl_down(v, off);
    return v;
}

// K1: LayerNorm over m rows (CM=256). One wave per row, float4 per thread.
__global__ __launch_bounds__(64) void ln_m_kernel(const float* __restrict__ m,
                                                  const float* __restrict__ w,
                                                  const float* __restrict__ b,
                                                  float* __restrict__ mn) {
    int row = blockIdx.x;
    int t = threadIdx.x;
    const float4* mrow = (const float4*)(m + (size_t)row * CM_DIM);
    float4 x = mrow[t];
    float s = x.x + x.y + x.z + x.w;
    float ss = x.x * x.x + x.y * x.y + x.z * x.z + x.w * x.w;
    s = wave_sum(s);
    ss = wave_sum(ss);
    s = __shfl(s, 0);
    ss = __shfl(ss, 0);
    float mean = s * (1.0f / CM_DIM);
    float var = ss * (1.0f / CM_DIM) - mean * mean;
    float rsig = rsqrtf(var + LN_EPS);
    float4 wv = ((const float4*)w)[t];
    float4 bv = ((const float4*)b)[t];
    float4 o;
    o.x = (x.x - mean) * rsig * wv.x + bv.x;
    o.y = (x.y - mean) * rsig * wv.y + bv.y;
    o.z = (x.z - mean) * rsig * wv.z + bv.z;
    o.w = (x.w - mean) * rsig * wv.w + bv.w;
    ((float4*)(mn + (size_t)row * CM_DIM))[t] = o;
}

// K2: LayerNorm over z rows (CZ=128) fused with bias = zn @ Wz.
// One wave per (q,k) pair. Output layout bias_t[h][k][q].
__global__ __launch_bounds__(64) void ln_z_bias_kernel(const float* __restrict__ z,
                                                       const float* __restrict__ w,
                                                       const float* __restrict__ b,
                                                       const float* __restrict__ Wz,
                                                       float* __restrict__ bias_t) {
    __shared__ __align__(16) float wz_t[CZ_DIM * H_DIM];  // transposed [h][c]
    int blk = blockIdx.x;
    int q = blk >> 8;
    int kk = blk & 255;
    int t = threadIdx.x;
    for (int idx = t; idx < CZ_DIM * H_DIM; idx += 64) {
        int h = idx >> 7;
        int c = idx & 127;
        wz_t[idx] = Wz[c * H_DIM + h];
    }
    __syncthreads();
    const float2* zrow = (const float2*)(z + ((size_t)q * R_DIM + kk) * CZ_DIM);
    float2 x = zrow[t];
    float s = x.x + x.y;
    float ss = x.x * x.x + x.y * x.y;
    s = wave_sum(s);
    ss = wave_sum(ss);
    s = __shfl(s, 0);
    ss = __shfl(ss, 0);
    float mean = s * (1.0f / CZ_DIM);
    float var = ss * (1.0f / CZ_DIM) - mean * mean;
    float rsig = rsqrtf(var + LN_EPS);
    int c0 = 2 * t, c1 = 2 * t + 1;
    float nv0 = (x.x - mean) * rsig * w[c0] + b[c0];
    float nv1 = (x.y - mean) * rsig * w[c1] + b[c1];
#pragma unroll
    for (int h = 0; h < H_DIM; h++) {
        float p = nv0 * wz_t[h * CZ_DIM + c0] + nv1 * wz_t[h * CZ_DIM + c1];
        p = wave_sum(p);
        if (t == 0) bias_t[((size_t)h * R_DIM + kk) * R_DIM + q] = p;
    }
}

// K3: fused projections  mn[32768,256] @ {Wq,Wk,Wv,Wg}[256,256].
// blockIdx.y in [0,16): which = y>>2 selects matrix, (y&3)*64 selects col tile.
__global__ __launch_bounds__(256) void proj_kernel(const float* __restrict__ A,
                                                   const float* __restrict__ Wq,
                                                   const float* __restrict__ Wk,
                                                   const float* __restrict__ Wv,
                                                   const float* __restrict__ Wg,
                                                   const float* __restrict__ bg,
                                                   float* __restrict__ qout,
                                                   float* __restrict__ kout,
                                                   float* __restrict__ vout,
                                                   float* __restrict__ gout) {
    __shared__ __align__(16) float As[16][64];  // transposed: As[k][m]
    __shared__ __align__(16) float Bs[16][64];
    int tile = blockIdx.y;
    int which = tile >> 2;
    int col0 = (tile & 3) * 64;
    int bm = blockIdx.x * 64;
    const float* W = (which == 0) ? Wq : (which == 1) ? Wk : (which == 2) ? Wv : Wg;
    float* Out = (which == 0) ? qout : (which == 1) ? kout : (which == 2) ? vout : gout;
    int tid = threadIdx.x;
    int tx = tid & 15, ty = tid >> 4;
    float acc[4][4] = {};
    int ar = tid >> 2, ac4 = (tid & 3) * 4;
    int br = tid >> 4, bc4 = (tid & 15) * 4;
    for (int k0 = 0; k0 < CM_DIM; k0 += 16) {
        float4 av = *(const float4*)(A + (size_t)(bm + ar) * CM_DIM + k0 + ac4);
        float4 bvv = *(const float4*)(W + (size_t)(k0 + br) * HC_DIM + col0 + bc4);
        __syncthreads();  // previous iter's LDS reads done
        As[ac4 + 0][ar] = av.x;
        As[ac4 + 1][ar] = av.y;
        As[ac4 + 2][ar] = av.z;
        As[ac4 + 3][ar] = av.w;
        *(float4*)&Bs[br][bc4] = bvv;
        __syncthreads();
#pragma unroll
        for (int kk = 0; kk < 16; kk++) {
            float4 a4 = *(const float4*)&As[kk][ty * 4];
            float4 b4 = *(const float4*)&Bs[kk][tx * 4];
            float aa[4] = {a4.x, a4.y, a4.z, a4.w};
            float bb[4] = {b4.x, b4.y, b4.z, b4.w};
#pragma unroll
            for (int i = 0; i < 4; i++)
#pragma unroll
                for (int j = 0; j < 4; j++) acc[i][j] = fmaf(aa[i], bb[j], acc[i][j]);
        }
    }
    const float qscale = 0.17677669529663687f;  // 32^-0.5
#pragma unroll
    for (int i = 0; i < 4; i++) {
        float4 o;
        float vals[4];
#pragma unroll
        for (int j = 0; j < 4; j++) {
            float v = acc[i][j];
            if (which == 0) {
                v *= qscale;
            } else if (which == 3) {
                v = v + bg[col0 + tx * 4 + j];
                v = 1.0f / (1.0f + __expf(-v));
            }
            vals[j] = v;
        }
        o.x = vals[0]; o.y = vals[1]; o.z = vals[2]; o.w = vals[3];
        *(float4*)(Out + (size_t)(bm + ty * 4 + i) * HC_DIM + col0 + tx * 4) = o;
    }
}

// K4: flash attention per (s,h). 256 threads, 1 q-row each. K/V/bias staged in LDS.
__global__ __launch_bounds__(256) void attn_kernel(const float* __restrict__ qv,
                                                   const float* __restrict__ kv,
                                                   const float* __restrict__ vv,
                                                   const float* __restrict__ bias_t,
                                                   float* __restrict__ oo) {
    int s = blockIdx.x, h = blockIdx.y;
    int qr = threadIdx.x;
    __shared__ __align__(16) float k_s[32][32];
    __shared__ __align__(16) float v_s[32][32];
    __shared__ __align__(16) float b_s[32 * 256];  // [j][q]

    float q_reg[32];
    const float* qp = qv + ((size_t)(s * R_DIM + qr) * H_DIM + h) * C_DIM;
#pragma unroll
    for (int i = 0; i < 8; i++) {
        float4 t4 = *(const float4*)(qp + i * 4);
        q_reg[i * 4 + 0] = t4.x;
        q_reg[i * 4 + 1] = t4.y;
        q_reg[i * 4 + 2] = t4.z;
        q_reg[i * 4 + 3] = t4.w;
    }
    float rm = -1e30f, l = 0.0f;
    float o_acc[32];
#pragma unroll
    for (int c = 0; c < 32; c++) o_acc[c] = 0.0f;

    int lj = qr >> 3, lc4 = (qr & 7) * 4;
    for (int k0 = 0; k0 < R_DIM; k0 += 32) {
        __syncthreads();
        const float* kp = kv + ((size_t)(s * R_DIM + k0 + lj) * H_DIM + h) * C_DIM + lc4;
        const float* vp = vv + ((size_t)(s * R_DIM + k0 + lj) * H_DIM + h) * C_DIM + lc4;
        *(float4*)&k_s[lj][lc4] = *(const float4*)kp;
        *(float4*)&v_s[lj][lc4] = *(const float4*)vp;
        const float* bp = bias_t + ((size_t)h * R_DIM + k0) * R_DIM;
#pragma unroll
        for (int i = 0; i < 8; i++) {
            int idx4 = qr + i * 256;
            *(float4*)&b_s[idx4 * 4] = *(const float4*)(bp + idx4 * 4);
        }
        __syncthreads();

        float lg[32];
#pragma unroll
        for (int j = 0; j < 32; j++) {
            float d = 0.0f;
#pragma unroll
            for (int c4 = 0; c4 < 8; c4++) {
                float4 kk4 = *(const float4*)&k_s[j][c4 * 4];
                d = fmaf(q_reg[c4 * 4 + 0], kk4.x, d);
                d = fmaf(q_reg[c4 * 4 + 1], kk4.y, d);
                d = fmaf(q_reg[c4 * 4 + 2], kk4.z, d);
                d = fmaf(q_reg[c4 * 4 + 3], kk4.w, d);
            }
            lg[j] = d + b_s[j * 256 + qr];
        }
        float tm = lg[0];
#pragma unroll
        for (int j = 1; j < 32; j++) tm = fmaxf(tm, lg[j]);
        float nm = fmaxf(rm, tm);
        float scale = __expf(rm - nm);
        l *= scale;
#pragma unroll
        for (int c = 0; c < 32; c++) o_acc[c] *= scale;
#pragma unroll
        for (int j = 0; j < 32; j++) {
            float p = __expf(lg[j] - nm);
            l += p;
#pragma unroll
            for (int c4 = 0; c4 < 8; c4++) {
                float4 vv4 = *(const float4*)&v_s[j][c4 * 4];
                o_acc[c4 * 4 + 0] = fmaf(p, vv4.x, o_acc[c4 * 4 + 0]);
                o_acc[c4 * 4 + 1] = fmaf(p, vv4.y, o_acc[c4 * 4 + 1]);
                o_acc[c4 * 4 + 2] = fmaf(p, vv4.z, o_acc[c4 * 4 + 2]);
                o_acc[c4 * 4 + 3] = fmaf(p, vv4.w, o_acc[c4 * 4 + 3]);
            }
        }
        rm = nm;
    }
    float inv = 1.0f / l;
    float* op = oo + ((size_t)(s * R_DIM + qr) * H_DIM + h) * C_DIM;
#pragma unroll
    for (int i = 0; i < 8; i++) {
        float4 o4;
        o4.x = o_acc[i * 4 + 0] * inv;
        o4.y = o_acc[i * 4 + 1] * inv;
        o4.z = o_acc[i * 4 + 2] * inv;
        o4.w = o_acc[i * 4 + 3] * inv;
        *(float4*)(op + i * 4) = o4;
    }
}

// K5: out = (g*o)[32768,256] @ Wo[256,256] + bo
__global__ __launch_bounds__(256) void out_kernel(const float* __restrict__ gg,
                                                  const float* __restrict__ oo,
                                                  const float* __restrict__ Wo,
                                                  const float* __restrict__ bo,
                                                  float* __restrict__ out) {
    __shared__ __align__(16) float As[16][64];
    __shared__ __align__(16) float Bs[16][64];
    int col0 = blockIdx.y * 64;
    int bm = blockIdx.x * 64;
    int tid = threadIdx.x;
    int tx = tid & 15, ty = tid >> 4;
    float acc[4][4] = {};
    int ar = tid >> 2, ac4 = (tid & 3) * 4;
    int br = tid >> 4, bc4 = (tid & 15) * 4;
    for (int k0 = 0; k0 < HC_DIM; k0 += 16) {
        size_t aoff = (size_t)(bm + ar) * HC_DIM + k0 + ac4;
        float4 g4 = *(const float4*)(gg + aoff);
        float4 o4 = *(const float4*)(oo + aoff);
        float4 bvv = *(const float4*)(Wo + (size_t)(k0 + br) * CM_DIM + col0 + bc4);
        __syncthreads();
        As[ac4 + 0][ar] = g4.x * o4.x;
        As[ac4 + 1][ar] = g4.y * o4.y;
        As[ac4 + 2][ar] = g4.z * o4.z;
        As[ac4 + 3][ar] = g4.w * o4.w;
        *(float4*)&Bs[br][bc4] = bvv;
        __syncthreads();
#pragma unroll
        for (int kk = 0; kk < 16; kk++) {
            float4 a4 = *(const float4*)&As[kk][ty * 4];
            float4 b4 = *(const float4*)&Bs[kk][tx * 4];
            float aa[4] = {a4.x, a4.y, a4.z, a4.w};
            float bb[4] = {b4.x, b4.y, b4.z, b4.w};
#pragma unroll
            for (int i = 0; i < 4; i++)
#pragma unroll
                for (int j = 0; j < 4; j++) acc[i][j] = fmaf(aa[i], bb[j], acc[i][j]);
        }
    }
#pragma unroll
    for (int i = 0; i < 4; i++) {
        float4 o;
        o.x = acc[i][0] + bo[col0 + tx * 4 + 0];
        o.y = acc[i][1] + bo[col0 + tx * 4 + 1];
        o.z = acc[i][2] + bo[col0 + tx * 4 + 2];
        o.w = acc[i][3] + bo[col0 + tx * 4 + 3];
        *(float4*)(out + (size_t)(bm + ty * 4 + i) * CM_DIM + col0 + tx * 4) = o;
    }
}

extern "C" void kernel_launch(void* const* d_in, const int* in_sizes, int n_in,
                              void* d_out, int out_size, void* d_ws, size_t ws_size,
                              hipStream_t stream) {
    const float* m = (const float*)d_in[0];
    const float* z = (const float*)d_in[1];
    const float* ln_m_w = (const float*)d_in[2];
    const float* ln_m_b = (const float*)d_in[3];
    const float* ln_z_w = (const float*)d_in[4];
    const float* ln_z_b = (const float*)d_in[5];
    const float* Wz = (const float*)d_in[6];
    const float* Wq = (const float*)d_in[7];
    const float* Wk = (const float*)d_in[8];
    const float* Wv = (const float*)d_in[9];
    const float* Wg = (const float*)d_in[10];
    const float* bg = (const float*)d_in[11];
    const float* Wo = (const float*)d_in[12];
    const float* bo = (const float*)d_in[13];
    float* out = (float*)d_out;

    float* ws = (float*)d_ws;
    const size_t NE = (size_t)S_DIM * R_DIM * CM_DIM;  // 8388608
    float* mn = ws;
    float* qq = ws + NE;
    float* kk = ws + 2 * NE;
    float* vv = ws + 3 * NE;
    float* gg = ws + 4 * NE;
    float* bias_t = ws + 5 * NE;  // H*R*R = 524288
    float* oo = ws;               // reuse mn space (mn dead after proj_kernel)

    hipLaunchKernelGGL(ln_m_kernel, dim3(S_DIM * R_DIM), dim3(64), 0, stream,
                       m, ln_m_w, ln_m_b, mn);
    hipLaunchKernelGGL(ln_z_bias_kernel, dim3(R_DIM * R_DIM), dim3(64), 0, stream,
                       z, ln_z_w, ln_z_b, Wz, bias_t);
    hipLaunchKernelGGL(proj_kernel, dim3(512, 16), dim3(256), 0, stream,
                       mn, Wq, Wk, Wv, Wg, bg, qq, kk, vv, gg);
    hipLaunchKernelGGL(attn_kernel, dim3(S_DIM, H_DIM), dim3(256), 0, stream,
                       qq, kk, vv, bias_t, oo);
    hipLaunchKernelGGL(out_kernel, dim3(512, 4), dim3(256), 0, stream,
                       gg, oo, Wo, bo, out);
}

// Round 4
// 254.201 us; speedup vs baseline: 2.6340x; 2.6340x over previous
//
#include <hip/hip_runtime.h>
#include <math.h>

#define S_DIM 128
#define R_DIM 256
#define CM_DIM 256
#define CZ_DIM 128
#define C_DIM 32
#define H_DIM 8
#define HC_DIM 256
#define LN_EPS 1e-5f

typedef _Float16 half8 __attribute__((ext_vector_type(8)));
typedef _Float16 half4 __attribute__((ext_vector_type(4)));
typedef float f32x4 __attribute__((ext_vector_type(4)));

__device__ __forceinline__ float wave_sum(float v) {
#pragma unroll
    for (int off = 32; off > 0; off >>= 1) v += __shfl_down(v, off);
    return v;
}

// K0: convert+retile weights: W[k][n] f32 -> W3[mat][kb][n][kk] fp16 (kb=k/32, kk=k%32)
__global__ __launch_bounds__(256) void convert_w_kernel(const float* __restrict__ Wq,
                                                        const float* __restrict__ Wk,
                                                        const float* __restrict__ Wv,
                                                        const float* __restrict__ Wg,
                                                        const float* __restrict__ Wo,
                                                        _Float16* __restrict__ w3) {
    int kb = blockIdx.x;   // 0..7
    int mat = blockIdx.y;  // 0..4
    const float* src = (mat == 0) ? Wq : (mat == 1) ? Wk : (mat == 2) ? Wv : (mat == 3) ? Wg : Wo;
    int n = threadIdx.x;
    _Float16 tmp[32];
#pragma unroll
    for (int kk = 0; kk < 32; kk++)
        tmp[kk] = (_Float16)src[(size_t)(kb * 32 + kk) * 256 + n];
    half8* dst = (half8*)(w3 + (size_t)mat * 65536 + (size_t)kb * 8192 + (size_t)n * 32);
#pragma unroll
    for (int i = 0; i < 4; i++) dst[i] = *(half8*)&tmp[i * 8];
}

// K1: LayerNorm m -> fp16. One wave per row.
__global__ __launch_bounds__(64) void ln_m_kernel(const float* __restrict__ m,
                                                  const float* __restrict__ w,
                                                  const float* __restrict__ b,
                                                  _Float16* __restrict__ mn) {
    int row = blockIdx.x;
    int t = threadIdx.x;
    const float4* mrow = (const float4*)(m + (size_t)row * CM_DIM);
    float4 x = mrow[t];
    float s = x.x + x.y + x.z + x.w;
    float ss = x.x * x.x + x.y * x.y + x.z * x.z + x.w * x.w;
    s = wave_sum(s);
    ss = wave_sum(ss);
    s = __shfl(s, 0);
    ss = __shfl(ss, 0);
    float mean = s * (1.0f / CM_DIM);
    float var = ss * (1.0f / CM_DIM) - mean * mean;
    float rsig = rsqrtf(var + LN_EPS);
    float4 wv = ((const float4*)w)[t];
    float4 bv = ((const float4*)b)[t];
    half4 o;
    o[0] = (_Float16)((x.x - mean) * rsig * wv.x + bv.x);
    o[1] = (_Float16)((x.y - mean) * rsig * wv.y + bv.y);
    o[2] = (_Float16)((x.z - mean) * rsig * wv.z + bv.z);
    o[3] = (_Float16)((x.w - mean) * rsig * wv.w + bv.w);
    *(half4*)(mn + (size_t)row * CM_DIM + t * 4) = o;
}

// K2: LayerNorm z + bias einsum. Output bias_t[h][q][k] f32.
__global__ __launch_bounds__(64) void ln_z_bias_kernel(const float* __restrict__ z,
                                                       const float* __restrict__ w,
                                                       const float* __restrict__ b,
                                                       const float* __restrict__ Wz,
                                                       float* __restrict__ bias_t) {
    __shared__ __align__(16) float wz_t[CZ_DIM * H_DIM];  // [h][c]
    int blk = blockIdx.x;
    int q = blk >> 8;
    int kk = blk & 255;
    int t = threadIdx.x;
    for (int idx = t; idx < CZ_DIM * H_DIM; idx += 64) {
        int h = idx >> 7;
        int c = idx & 127;
        wz_t[idx] = Wz[c * H_DIM + h];
    }
    __syncthreads();
    const float2* zrow = (const float2*)(z + ((size_t)q * R_DIM + kk) * CZ_DIM);
    float2 x = zrow[t];
    float s = x.x + x.y;
    float ss = x.x * x.x + x.y * x.y;
    s = wave_sum(s);
    ss = wave_sum(ss);
    s = __shfl(s, 0);
    ss = __shfl(ss, 0);
    float mean = s * (1.0f / CZ_DIM);
    float var = ss * (1.0f / CZ_DIM) - mean * mean;
    float rsig = rsqrtf(var + LN_EPS);
    int c0 = 2 * t, c1 = 2 * t + 1;
    float nv0 = (x.x - mean) * rsig * w[c0] + b[c0];
    float nv1 = (x.y - mean) * rsig * w[c1] + b[c1];
#pragma unroll
    for (int h = 0; h < H_DIM; h++) {
        float p = nv0 * wz_t[h * CZ_DIM + c0] + nv1 * wz_t[h * CZ_DIM + c1];
        p = wave_sum(p);
        if (t == 0) bias_t[((size_t)h * R_DIM + q) * R_DIM + kk] = p;
    }
}

// K3: MFMA projections. Block tile 64Mx256N, 4 waves (wave -> 64-col slab).
__global__ __launch_bounds__(256, 3) void proj_mfma_kernel(const _Float16* __restrict__ A,
                                                           const _Float16* __restrict__ w3,
                                                           const float* __restrict__ bg,
                                                           _Float16* __restrict__ qh,
                                                           _Float16* __restrict__ kh,
                                                           _Float16* __restrict__ vh,
                                                           _Float16* __restrict__ gh) {
    __shared__ _Float16 As[64][40];
    __shared__ _Float16 Bs[256][40];
    int mat = blockIdx.y;
    int m0 = blockIdx.x * 64;
    const _Float16* W = w3 + (size_t)mat * 65536;
    _Float16* Out = (mat == 0) ? qh : (mat == 1) ? kh : (mat == 2) ? vh : gh;
    int tid = threadIdx.x;
    int lane = tid & 63, wave = tid >> 6;
    int lrow = lane & 15, lk8 = (lane >> 4) * 8;
    f32x4 acc[4][4];
#pragma unroll
    for (int i = 0; i < 4; i++)
#pragma unroll
        for (int j = 0; j < 4; j++) acc[i][j] = (f32x4){0.f, 0.f, 0.f, 0.f};

    for (int kb = 0; kb < 8; kb++) {
        half8 av = *(const half8*)(A + (size_t)(m0 + (tid >> 2)) * 256 + kb * 32 + (tid & 3) * 8);
        half8 bv[4];
#pragma unroll
        for (int i = 0; i < 4; i++)
            bv[i] = *(const half8*)(W + (size_t)kb * 8192 + (size_t)(i * 256 + tid) * 8);
        __syncthreads();
        *(half8*)&As[tid >> 2][(tid & 3) * 8] = av;
#pragma unroll
        for (int i = 0; i < 4; i++) {
            int c = i * 256 + tid;
            *(half8*)&Bs[c >> 2][(c & 3) * 8] = bv[i];
        }
        __syncthreads();
        half8 af[4], bf[4];
#pragma unroll
        for (int mf = 0; mf < 4; mf++) af[mf] = *(half8*)&As[mf * 16 + lrow][lk8];
#pragma unroll
        for (int nf = 0; nf < 4; nf++) bf[nf] = *(half8*)&Bs[wave * 64 + nf * 16 + lrow][lk8];
#pragma unroll
        for (int mf = 0; mf < 4; mf++)
#pragma unroll
            for (int nf = 0; nf < 4; nf++)
                acc[mf][nf] = __builtin_amdgcn_mfma_f32_16x16x32_f16(af[mf], bf[nf], acc[mf][nf], 0, 0, 0);
    }
    const float qscale = 0.17677669529663687f;  // 32^-0.5
#pragma unroll
    for (int mf = 0; mf < 4; mf++)
#pragma unroll
        for (int nf = 0; nf < 4; nf++)
#pragma unroll
            for (int ri = 0; ri < 4; ri++) {
                int row = m0 + mf * 16 + (lane >> 4) * 4 + ri;
                int col = wave * 64 + nf * 16 + lrow;
                float v = acc[mf][nf][ri];
                if (mat == 0) v *= qscale;
                if (mat == 3) v = 1.0f / (1.0f + __expf(-(v + bg[col])));
                Out[(size_t)row * 256 + col] = (_Float16)v;
            }
}

// K4: MFMA flash attention per (s,h). 4 waves x 64 q-rows, 64-key tiles.
__global__ __launch_bounds__(256, 2) void attn_mfma_kernel(const _Float16* __restrict__ qh,
                                                           const _Float16* __restrict__ kh,
                                                           const _Float16* __restrict__ vh,
                                                           const float* __restrict__ bias_t,
                                                           _Float16* __restrict__ oh) {
    __shared__ _Float16 K_s[64][40];
    __shared__ _Float16 VT_s[32][72];
    __shared__ _Float16 P_s[4][64][72];
    int s = blockIdx.x, h = blockIdx.y;
    int tid = threadIdx.x, lane = tid & 63, wave = tid >> 6;
    int lrow = lane & 15, lk8 = (lane >> 4) * 8;
    int q0 = wave * 64;

    half8 qfr[4];
#pragma unroll
    for (int qf = 0; qf < 4; qf++)
        qfr[qf] = *(const half8*)(qh + (size_t)(s * 256 + q0 + qf * 16 + lrow) * 256 + h * 32 + lk8);

    f32x4 oacc[4][2];
    float m_run[4][4], l_run[4][4];
#pragma unroll
    for (int qf = 0; qf < 4; qf++) {
#pragma unroll
        for (int cf = 0; cf < 2; cf++) oacc[qf][cf] = (f32x4){0.f, 0.f, 0.f, 0.f};
#pragma unroll
        for (int ri = 0; ri < 4; ri++) { m_run[qf][ri] = -1e30f; l_run[qf][ri] = 0.f; }
    }

    for (int kb = 0; kb < 4; kb++) {
        int key = tid >> 2, koff = (tid & 3) * 8;
        half8 kv_ = *(const half8*)(kh + (size_t)(s * 256 + kb * 64 + key) * 256 + h * 32 + koff);
        int vkey = tid & 63, c0 = (tid >> 6) * 8;
        half8 vv_ = *(const half8*)(vh + (size_t)(s * 256 + kb * 64 + vkey) * 256 + h * 32 + c0);
        __syncthreads();  // prior tile's K_s/VT_s reads complete
        *(half8*)&K_s[key][koff] = kv_;
#pragma unroll
        for (int j = 0; j < 8; j++) VT_s[c0 + j][vkey] = vv_[j];
        __syncthreads();

        // QK^T
        f32x4 sf[4][4];
        half8 kfr[4];
#pragma unroll
        for (int kf = 0; kf < 4; kf++) kfr[kf] = *(half8*)&K_s[kf * 16 + lrow][lk8];
#pragma unroll
        for (int qf = 0; qf < 4; qf++)
#pragma unroll
            for (int kf = 0; kf < 4; kf++) {
                f32x4 zero = (f32x4){0.f, 0.f, 0.f, 0.f};
                sf[qf][kf] = __builtin_amdgcn_mfma_f32_16x16x32_f16(qfr[qf], kfr[kf], zero, 0, 0, 0);
            }
        // + pair bias (f32, from L2)
#pragma unroll
        for (int qf = 0; qf < 4; qf++)
#pragma unroll
            for (int kf = 0; kf < 4; kf++)
#pragma unroll
                for (int ri = 0; ri < 4; ri++) {
                    int row = q0 + qf * 16 + (lane >> 4) * 4 + ri;
                    int keyg = kb * 64 + kf * 16 + lrow;
                    sf[qf][kf][ri] += bias_t[((size_t)(h * 256 + row)) * 256 + keyg];
                }
        // online softmax (row lives across the 16 lanes of a group)
#pragma unroll
        for (int qf = 0; qf < 4; qf++)
#pragma unroll
            for (int ri = 0; ri < 4; ri++) {
                float x = fmaxf(fmaxf(sf[qf][0][ri], sf[qf][1][ri]),
                                fmaxf(sf[qf][2][ri], sf[qf][3][ri]));
                x = fmaxf(x, __shfl_xor(x, 1));
                x = fmaxf(x, __shfl_xor(x, 2));
                x = fmaxf(x, __shfl_xor(x, 4));
                x = fmaxf(x, __shfl_xor(x, 8));
                float nm = fmaxf(m_run[qf][ri], x);
                float sc = __expf(m_run[qf][ri] - nm);
                m_run[qf][ri] = nm;
                l_run[qf][ri] *= sc;
#pragma unroll
                for (int cf = 0; cf < 2; cf++) oacc[qf][cf][ri] *= sc;
                float rs = 0.f;
#pragma unroll
                for (int kf = 0; kf < 4; kf++) {
                    float p = __expf(sf[qf][kf][ri] - nm);
                    sf[qf][kf][ri] = p;
                    rs += p;
                }
                rs += __shfl_xor(rs, 1);
                rs += __shfl_xor(rs, 2);
                rs += __shfl_xor(rs, 4);
                rs += __shfl_xor(rs, 8);
                l_run[qf][ri] += rs;
            }
        // P: D-layout -> A-layout via per-wave LDS round-trip
#pragma unroll
        for (int qf = 0; qf < 4; qf++)
#pragma unroll
            for (int kf = 0; kf < 4; kf++)
#pragma unroll
                for (int ri = 0; ri < 4; ri++)
                    P_s[wave][qf * 16 + (lane >> 4) * 4 + ri][kf * 16 + lrow] =
                        (_Float16)sf[qf][kf][ri];
        // PV
#pragma unroll
        for (int ks = 0; ks < 2; ks++) {
            half8 vb[2];
#pragma unroll
            for (int cf = 0; cf < 2; cf++) vb[cf] = *(half8*)&VT_s[cf * 16 + lrow][ks * 32 + lk8];
#pragma unroll
            for (int qf = 0; qf < 4; qf++) {
                half8 pa = *(half8*)&P_s[wave][qf * 16 + lrow][ks * 32 + lk8];
#pragma unroll
                for (int cf = 0; cf < 2; cf++)
                    oacc[qf][cf] = __builtin_amdgcn_mfma_f32_16x16x32_f16(pa, vb[cf], oacc[qf][cf], 0, 0, 0);
            }
        }
    }
#pragma unroll
    for (int qf = 0; qf < 4; qf++)
#pragma unroll
        for (int ri = 0; ri < 4; ri++) {
            float inv = 1.0f / l_run[qf][ri];
            int row = q0 + qf * 16 + (lane >> 4) * 4 + ri;
#pragma unroll
            for (int cf = 0; cf < 2; cf++)
                oh[(size_t)(s * 256 + row) * 256 + h * 32 + cf * 16 + lrow] =
                    (_Float16)(oacc[qf][cf][ri] * inv);
        }
}

// K5: out = (g .* o) @ Wo + bo, fp16 MFMA, f32 out.
__global__ __launch_bounds__(256, 3) void out_mfma_kernel(const _Float16* __restrict__ gh,
                                                          const _Float16* __restrict__ oh,
                                                          const _Float16* __restrict__ w3o,
                                                          const float* __restrict__ bo,
                                                          float* __restrict__ out) {
    __shared__ _Float16 As[64][40];
    __shared__ _Float16 Bs[256][40];
    int m0 = blockIdx.x * 64;
    int tid = threadIdx.x;
    int lane = tid & 63, wave = tid >> 6;
    int lrow = lane & 15, lk8 = (lane >> 4) * 8;
    f32x4 acc[4][4];
#pragma unroll
    for (int i = 0; i < 4; i++)
#pragma unroll
        for (int j = 0; j < 4; j++) acc[i][j] = (f32x4){0.f, 0.f, 0.f, 0.f};

    for (int kb = 0; kb < 8; kb++) {
        size_t aoff = (size_t)(m0 + (tid >> 2)) * 256 + kb * 32 + (tid & 3) * 8;
        half8 gv = *(const half8*)(gh + aoff);
        half8 ov = *(const half8*)(oh + aoff);
        half8 av = gv * ov;
        half8 bv[4];
#pragma unroll
        for (int i = 0; i < 4; i++)
            bv[i] = *(const half8*)(w3o + (size_t)kb * 8192 + (size_t)(i * 256 + tid) * 8);
        __syncthreads();
        *(half8*)&As[tid >> 2][(tid & 3) * 8] = av;
#pragma unroll
        for (int i = 0; i < 4; i++) {
            int c = i * 256 + tid;
            *(half8*)&Bs[c >> 2][(c & 3) * 8] = bv[i];
        }
        __syncthreads();
        half8 af[4], bf[4];
#pragma unroll
        for (int mf = 0; mf < 4; mf++) af[mf] = *(half8*)&As[mf * 16 + lrow][lk8];
#pragma unroll
        for (int nf = 0; nf < 4; nf++) bf[nf] = *(half8*)&Bs[wave * 64 + nf * 16 + lrow][lk8];
#pragma unroll
        for (int mf = 0; mf < 4; mf++)
#pragma unroll
            for (int nf = 0; nf < 4; nf++)
                acc[mf][nf] = __builtin_amdgcn_mfma_f32_16x16x32_f16(af[mf], bf[nf], acc[mf][nf], 0, 0, 0);
    }
#pragma unroll
    for (int mf = 0; mf < 4; mf++)
#pragma unroll
        for (int nf = 0; nf < 4; nf++)
#pragma unroll
            for (int ri = 0; ri < 4; ri++) {
                int row = m0 + mf * 16 + (lane >> 4) * 4 + ri;
                int col = wave * 64 + nf * 16 + lrow;
                out[(size_t)row * 256 + col] = acc[mf][nf][ri] + bo[col];
            }
}

extern "C" void kernel_launch(void* const* d_in, const int* in_sizes, int n_in,
                              void* d_out, int out_size, void* d_ws, size_t ws_size,
                              hipStream_t stream) {
    const float* m = (const float*)d_in[0];
    const float* z = (const float*)d_in[1];
    const float* ln_m_w = (const float*)d_in[2];
    const float* ln_m_b = (const float*)d_in[3];
    const float* ln_z_w = (const float*)d_in[4];
    const float* ln_z_b = (const float*)d_in[5];
    const float* Wz = (const float*)d_in[6];
    const float* Wq = (const float*)d_in[7];
    const float* Wk = (const float*)d_in[8];
    const float* Wv = (const float*)d_in[9];
    const float* Wg = (const float*)d_in[10];
    const float* bg = (const float*)d_in[11];
    const float* Wo = (const float*)d_in[12];
    const float* bo = (const float*)d_in[13];
    float* out = (float*)d_out;

    const size_t NE = (size_t)S_DIM * R_DIM * CM_DIM;  // 8388608
    _Float16* hb = (_Float16*)d_ws;
    _Float16* mn_h = hb;
    _Float16* qh = hb + NE;
    _Float16* kh = hb + 2 * NE;
    _Float16* vh = hb + 3 * NE;
    _Float16* gh = hb + 4 * NE;
    _Float16* oh = hb + 5 * NE;
    _Float16* w3 = hb + 6 * NE;                         // 5*65536 halves
    float* bias_t = (float*)(hb + 6 * NE + 5 * 65536);  // H*R*R f32

    hipLaunchKernelGGL(convert_w_kernel, dim3(8, 5), dim3(256), 0, stream,
                       Wq, Wk, Wv, Wg, Wo, w3);
    hipLaunchKernelGGL(ln_m_kernel, dim3(S_DIM * R_DIM), dim3(64), 0, stream,
                       m, ln_m_w, ln_m_b, mn_h);
    hipLaunchKernelGGL(ln_z_bias_kernel, dim3(R_DIM * R_DIM), dim3(64), 0, stream,
                       z, ln_z_w, ln_z_b, Wz, bias_t);
    hipLaunchKernelGGL(proj_mfma_kernel, dim3(512, 4), dim3(256), 0, stream,
                       mn_h, w3, bg, qh, kh, vh, gh);
    hipLaunchKernelGGL(attn_mfma_kernel, dim3(S_DIM, H_DIM), dim3(256), 0, stream,
                       qh, kh, vh, bias_t, oh);
    hipLaunchKernelGGL(out_mfma_kernel, dim3(512), dim3(256), 0, stream,
                       gh, oh, w3 + 4 * 65536, bo, out);  // FIX: was w3 (Wq!) — pass Wo block
}

// Round 5
// 149.281 us; speedup vs baseline: 4.4853x; 1.7028x over previous
//
#include <hip/hip_runtime.h>
#include <math.h>

#define S_DIM 128
#define R_DIM 256
#define CM_DIM 256
#define CZ_DIM 128
#define C_DIM 32
#define H_DIM 8
#define HC_DIM 256
#define LN_EPS 1e-5f
#define ZPAD 132

typedef _Float16 half8 __attribute__((ext_vector_type(8)));
typedef _Float16 half4 __attribute__((ext_vector_type(4)));
typedef float f32x4 __attribute__((ext_vector_type(4)));

__device__ __forceinline__ float wave_sum(float v) {
#pragma unroll
    for (int off = 32; off > 0; off >>= 1) v += __shfl_down(v, off);
    return v;
}

// K0: convert+retile weights: W[k][n] f32 -> W3[mat][kb][n][kk] fp16 (kb=k/32, kk=k%32)
__global__ __launch_bounds__(256) void convert_w_kernel(const float* __restrict__ Wq,
                                                        const float* __restrict__ Wk,
                                                        const float* __restrict__ Wv,
                                                        const float* __restrict__ Wg,
                                                        const float* __restrict__ Wo,
                                                        _Float16* __restrict__ w3) {
    int kb = blockIdx.x;   // 0..7
    int mat = blockIdx.y;  // 0..4
    const float* src = (mat == 0) ? Wq : (mat == 1) ? Wk : (mat == 2) ? Wv : (mat == 3) ? Wg : Wo;
    int n = threadIdx.x;
    _Float16 tmp[32];
#pragma unroll
    for (int kk = 0; kk < 32; kk++)
        tmp[kk] = (_Float16)src[(size_t)(kb * 32 + kk) * 256 + n];
    half8* dst = (half8*)(w3 + (size_t)mat * 65536 + (size_t)kb * 8192 + (size_t)n * 32);
#pragma unroll
    for (int i = 0; i < 4; i++) dst[i] = *(half8*)&tmp[i * 8];
}

// K0b: precompute u[h][c] = ln_z_w[c]*Wz[c][h] (padded rows ZPAD), U[h], B[h].
__global__ __launch_bounds__(64) void prep_wz_kernel(const float* __restrict__ w,
                                                     const float* __restrict__ b,
                                                     const float* __restrict__ Wz,
                                                     float* __restrict__ u_g,
                                                     float* __restrict__ UB) {
    int lane = threadIdx.x;
    float w0 = w[lane], w1 = w[lane + 64];
    float b0 = b[lane], b1 = b[lane + 64];
#pragma unroll
    for (int h = 0; h < H_DIM; h++) {
        float wz0 = Wz[lane * H_DIM + h], wz1 = Wz[(lane + 64) * H_DIM + h];
        float u0 = w0 * wz0, u1 = w1 * wz1;
        u_g[h * ZPAD + lane] = u0;
        u_g[h * ZPAD + lane + 64] = u1;
        float U = wave_sum(u0 + u1);
        float B = wave_sum(b0 * wz0 + b1 * wz1);
        if (lane == 0) { UB[h] = U; UB[8 + h] = B; }
    }
}

// K1: LayerNorm m -> fp16. One wave per row.
__global__ __launch_bounds__(64) void ln_m_kernel(const float* __restrict__ m,
                                                  const float* __restrict__ w,
                                                  const float* __restrict__ b,
                                                  _Float16* __restrict__ mn) {
    int row = blockIdx.x;
    int t = threadIdx.x;
    const float4* mrow = (const float4*)(m + (size_t)row * CM_DIM);
    float4 x = mrow[t];
    float s = x.x + x.y + x.z + x.w;
    float ss = x.x * x.x + x.y * x.y + x.z * x.z + x.w * x.w;
    s = wave_sum(s);
    ss = wave_sum(ss);
    s = __shfl(s, 0);
    ss = __shfl(ss, 0);
    float mean = s * (1.0f / CM_DIM);
    float var = ss * (1.0f / CM_DIM) - mean * mean;
    float rsig = rsqrtf(var + LN_EPS);
    float4 wv = ((const float4*)w)[t];
    float4 bv = ((const float4*)b)[t];
    half4 o;
    o[0] = (_Float16)((x.x - mean) * rsig * wv.x + bv.x);
    o[1] = (_Float16)((x.y - mean) * rsig * wv.y + bv.y);
    o[2] = (_Float16)((x.z - mean) * rsig * wv.z + bv.z);
    o[3] = (_Float16)((x.w - mean) * rsig * wv.w + bv.w);
    *(half4*)(mn + (size_t)row * CM_DIM + t * 4) = o;
}

// K2: LN(z) folded into bias dot: bias_h = rsig*(A_h - mu*U_h) + B_h.
// 1024 blocks x 256 threads; 64 rows/block staged in LDS; thread (r,p) does 2 h-dots.
// No cross-lane ops. Output bias_t[h][q][k] f32.
__global__ __launch_bounds__(256) void ln_z_bias_kernel(const float* __restrict__ z,
                                                        const float* __restrict__ u_g,
                                                        const float* __restrict__ UB,
                                                        float* __restrict__ bias_t) {
    __shared__ __align__(16) float zt[64 * ZPAD];
    __shared__ __align__(16) float ut[8 * ZPAD];
    __shared__ float UBs[16];
    int tid = threadIdx.x;
    int row0 = blockIdx.x * 64;  // flattened (q*256+k)
    for (int i = tid; i < 8 * ZPAD; i += 256) ut[i] = u_g[i];
    if (tid < 16) UBs[tid] = UB[tid];
    const float4* zsrc = (const float4*)(z + (size_t)row0 * CZ_DIM);
#pragma unroll
    for (int i = 0; i < 8; i++) {
        int idx = tid + i * 256;  // float4 index in 64x128 tile
        float4 v = zsrc[idx];
        int r = idx >> 5, c4 = (idx & 31) * 4;
        *(float4*)&zt[r * ZPAD + c4] = v;
    }
    __syncthreads();
    int r = tid >> 2, p = tid & 3;
    const float* zr = &zt[r * ZPAD];
    const float* u0p = &ut[p * ZPAD];
    const float* u1p = &ut[(p + 4) * ZPAD];
    float s = 0.f, ss = 0.f, a0 = 0.f, a1 = 0.f;
#pragma unroll
    for (int c = 0; c < CZ_DIM; c += 4) {
        float4 x = *(const float4*)&zr[c];
        float4 uu0 = *(const float4*)&u0p[c];
        float4 uu1 = *(const float4*)&u1p[c];
        s += x.x + x.y + x.z + x.w;
        ss += x.x * x.x + x.y * x.y + x.z * x.z + x.w * x.w;
        a0 += x.x * uu0.x + x.y * uu0.y + x.z * uu0.z + x.w * uu0.w;
        a1 += x.x * uu1.x + x.y * uu1.y + x.z * uu1.z + x.w * uu1.w;
    }
    float mu = s * (1.0f / CZ_DIM);
    float var = ss * (1.0f / CZ_DIM) - mu * mu;
    float rsig = rsqrtf(var + LN_EPS);
    int row = row0 + r;
    bias_t[(size_t)p * 65536 + row] = rsig * (a0 - mu * UBs[p]) + UBs[8 + p];
    bias_t[(size_t)(p + 4) * 65536 + row] = rsig * (a1 - mu * UBs[12 + p]) + UBs[12 + p];
}

// K3: MFMA projections. Block tile 64Mx256N, 4 waves (wave -> 64-col slab).
__global__ __launch_bounds__(256, 3) void proj_mfma_kernel(const _Float16* __restrict__ A,
                                                           const _Float16* __restrict__ w3,
                                                           const float* __restrict__ bg,
                                                           _Float16* __restrict__ qh,
                                                           _Float16* __restrict__ kh,
                                                           _Float16* __restrict__ vh,
                                                           _Float16* __restrict__ gh) {
    __shared__ _Float16 As[64][40];
    __shared__ _Float16 Bs[256][40];
    int mat = blockIdx.y;
    int m0 = blockIdx.x * 64;
    const _Float16* W = w3 + (size_t)mat * 65536;
    _Float16* Out = (mat == 0) ? qh : (mat == 1) ? kh : (mat == 2) ? vh : gh;
    int tid = threadIdx.x;
    int lane = tid & 63, wave = tid >> 6;
    int lrow = lane & 15, lk8 = (lane >> 4) * 8;
    f32x4 acc[4][4];
#pragma unroll
    for (int i = 0; i < 4; i++)
#pragma unroll
        for (int j = 0; j < 4; j++) acc[i][j] = (f32x4){0.f, 0.f, 0.f, 0.f};

    for (int kb = 0; kb < 8; kb++) {
        half8 av = *(const half8*)(A + (size_t)(m0 + (tid >> 2)) * 256 + kb * 32 + (tid & 3) * 8);
        half8 bv[4];
#pragma unroll
        for (int i = 0; i < 4; i++)
            bv[i] = *(const half8*)(W + (size_t)kb * 8192 + (size_t)(i * 256 + tid) * 8);
        __syncthreads();
        *(half8*)&As[tid >> 2][(tid & 3) * 8] = av;
#pragma unroll
        for (int i = 0; i < 4; i++) {
            int c = i * 256 + tid;
            *(half8*)&Bs[c >> 2][(c & 3) * 8] = bv[i];
        }
        __syncthreads();
        half8 af[4], bf[4];
#pragma unroll
        for (int mf = 0; mf < 4; mf++) af[mf] = *(half8*)&As[mf * 16 + lrow][lk8];
#pragma unroll
        for (int nf = 0; nf < 4; nf++) bf[nf] = *(half8*)&Bs[wave * 64 + nf * 16 + lrow][lk8];
#pragma unroll
        for (int mf = 0; mf < 4; mf++)
#pragma unroll
            for (int nf = 0; nf < 4; nf++)
                acc[mf][nf] = __builtin_amdgcn_mfma_f32_16x16x32_f16(af[mf], bf[nf], acc[mf][nf], 0, 0, 0);
    }
    const float qscale = 0.17677669529663687f;  // 32^-0.5
#pragma unroll
    for (int mf = 0; mf < 4; mf++)
#pragma unroll
        for (int nf = 0; nf < 4; nf++)
#pragma unroll
            for (int ri = 0; ri < 4; ri++) {
                int row = m0 + mf * 16 + (lane >> 4) * 4 + ri;
                int col = wave * 64 + nf * 16 + lrow;
                float v = acc[mf][nf][ri];
                if (mat == 0) v *= qscale;
                if (mat == 3) v = 1.0f / (1.0f + __expf(-(v + bg[col])));
                Out[(size_t)row * 256 + col] = (_Float16)v;
            }
}

// K4: MFMA flash attention per (s,h). 4 waves x 64 q-rows, 64-key tiles.
__global__ __launch_bounds__(256, 2) void attn_mfma_kernel(const _Float16* __restrict__ qh,
                                                           const _Float16* __restrict__ kh,
                                                           const _Float16* __restrict__ vh,
                                                           const float* __restrict__ bias_t,
                                                           _Float16* __restrict__ oh) {
    __shared__ _Float16 K_s[64][40];
    __shared__ _Float16 VT_s[32][72];
    __shared__ _Float16 P_s[4][64][72];
    int s = blockIdx.x, h = blockIdx.y;
    int tid = threadIdx.x, lane = tid & 63, wave = tid >> 6;
    int lrow = lane & 15, lk8 = (lane >> 4) * 8;
    int q0 = wave * 64;

    half8 qfr[4];
#pragma unroll
    for (int qf = 0; qf < 4; qf++)
        qfr[qf] = *(const half8*)(qh + (size_t)(s * 256 + q0 + qf * 16 + lrow) * 256 + h * 32 + lk8);

    f32x4 oacc[4][2];
    float m_run[4][4], l_run[4][4];
#pragma unroll
    for (int qf = 0; qf < 4; qf++) {
#pragma unroll
        for (int cf = 0; cf < 2; cf++) oacc[qf][cf] = (f32x4){0.f, 0.f, 0.f, 0.f};
#pragma unroll
        for (int ri = 0; ri < 4; ri++) { m_run[qf][ri] = -1e30f; l_run[qf][ri] = 0.f; }
    }

    for (int kb = 0; kb < 4; kb++) {
        int key = tid >> 2, koff = (tid & 3) * 8;
        half8 kv_ = *(const half8*)(kh + (size_t)(s * 256 + kb * 64 + key) * 256 + h * 32 + koff);
        int vkey = tid & 63, c0 = (tid >> 6) * 8;
        half8 vv_ = *(const half8*)(vh + (size_t)(s * 256 + kb * 64 + vkey) * 256 + h * 32 + c0);
        __syncthreads();  // prior tile's K_s/VT_s reads complete
        *(half8*)&K_s[key][koff] = kv_;
#pragma unroll
        for (int j = 0; j < 8; j++) VT_s[c0 + j][vkey] = vv_[j];
        __syncthreads();

        // QK^T
        f32x4 sf[4][4];
        half8 kfr[4];
#pragma unroll
        for (int kf = 0; kf < 4; kf++) kfr[kf] = *(half8*)&K_s[kf * 16 + lrow][lk8];
#pragma unroll
        for (int qf = 0; qf < 4; qf++)
#pragma unroll
            for (int kf = 0; kf < 4; kf++) {
                f32x4 zero = (f32x4){0.f, 0.f, 0.f, 0.f};
                sf[qf][kf] = __builtin_amdgcn_mfma_f32_16x16x32_f16(qfr[qf], kfr[kf], zero, 0, 0, 0);
            }
        // + pair bias (f32, from L2)
#pragma unroll
        for (int qf = 0; qf < 4; qf++)
#pragma unroll
            for (int kf = 0; kf < 4; kf++)
#pragma unroll
                for (int ri = 0; ri < 4; ri++) {
                    int row = q0 + qf * 16 + (lane >> 4) * 4 + ri;
                    int keyg = kb * 64 + kf * 16 + lrow;
                    sf[qf][kf][ri] += bias_t[((size_t)(h * 256 + row)) * 256 + keyg];
                }
        // online softmax (row lives across the 16 lanes of a group)
#pragma unroll
        for (int qf = 0; qf < 4; qf++)
#pragma unroll
            for (int ri = 0; ri < 4; ri++) {
                float x = fmaxf(fmaxf(sf[qf][0][ri], sf[qf][1][ri]),
                                fmaxf(sf[qf][2][ri], sf[qf][3][ri]));
                x = fmaxf(x, __shfl_xor(x, 1));
                x = fmaxf(x, __shfl_xor(x, 2));
                x = fmaxf(x, __shfl_xor(x, 4));
                x = fmaxf(x, __shfl_xor(x, 8));
                float nm = fmaxf(m_run[qf][ri], x);
                float sc = __expf(m_run[qf][ri] - nm);
                m_run[qf][ri] = nm;
                l_run[qf][ri] *= sc;
#pragma unroll
                for (int cf = 0; cf < 2; cf++) oacc[qf][cf][ri] *= sc;
                float rs = 0.f;
#pragma unroll
                for (int kf = 0; kf < 4; kf++) {
                    float p = __expf(sf[qf][kf][ri] - nm);
                    sf[qf][kf][ri] = p;
                    rs += p;
                }
                rs += __shfl_xor(rs, 1);
                rs += __shfl_xor(rs, 2);
                rs += __shfl_xor(rs, 4);
                rs += __shfl_xor(rs, 8);
                l_run[qf][ri] += rs;
            }
        // P: D-layout -> A-layout via per-wave LDS round-trip
#pragma unroll
        for (int qf = 0; qf < 4; qf++)
#pragma unroll
            for (int kf = 0; kf < 4; kf++)
#pragma unroll
                for (int ri = 0; ri < 4; ri++)
                    P_s[wave][qf * 16 + (lane >> 4) * 4 + ri][kf * 16 + lrow] =
                        (_Float16)sf[qf][kf][ri];
        // PV
#pragma unroll
        for (int ks = 0; ks < 2; ks++) {
            half8 vb[2];
#pragma unroll
            for (int cf = 0; cf < 2; cf++) vb[cf] = *(half8*)&VT_s[cf * 16 + lrow][ks * 32 + lk8];
#pragma unroll
            for (int qf = 0; qf < 4; qf++) {
                half8 pa = *(half8*)&P_s[wave][qf * 16 + lrow][ks * 32 + lk8];
#pragma unroll
                for (int cf = 0; cf < 2; cf++)
                    oacc[qf][cf] = __builtin_amdgcn_mfma_f32_16x16x32_f16(pa, vb[cf], oacc[qf][cf], 0, 0, 0);
            }
        }
    }
#pragma unroll
    for (int qf = 0; qf < 4; qf++)
#pragma unroll
        for (int ri = 0; ri < 4; ri++) {
            float inv = 1.0f / l_run[qf][ri];
            int row = q0 + qf * 16 + (lane >> 4) * 4 + ri;
#pragma unroll
            for (int cf = 0; cf < 2; cf++)
                oh[(size_t)(s * 256 + row) * 256 + h * 32 + cf * 16 + lrow] =
                    (_Float16)(oacc[qf][cf][ri] * inv);
        }
}

// K5: out = (g .* o) @ Wo + bo, fp16 MFMA, f32 out.
__global__ __launch_bounds__(256, 3) void out_mfma_kernel(const _Float16* __restrict__ gh,
                                                          const _Float16* __restrict__ oh,
                                                          const _Float16* __restrict__ w3o,
                                                          const float* __restrict__ bo,
                                                          float* __restrict__ out) {
    __shared__ _Float16 As[64][40];
    __shared__ _Float16 Bs[256][40];
    int m0 = blockIdx.x * 64;
    int tid = threadIdx.x;
    int lane = tid & 63, wave = tid >> 6;
    int lrow = lane & 15, lk8 = (lane >> 4) * 8;
    f32x4 acc[4][4];
#pragma unroll
    for (int i = 0; i < 4; i++)
#pragma unroll
        for (int j = 0; j < 4; j++) acc[i][j] = (f32x4){0.f, 0.f, 0.f, 0.f};

    for (int kb = 0; kb < 8; kb++) {
        size_t aoff = (size_t)(m0 + (tid >> 2)) * 256 + kb * 32 + (tid & 3) * 8;
        half8 gv = *(const half8*)(gh + aoff);
        half8 ov = *(const half8*)(oh + aoff);
        half8 av = gv * ov;
        half8 bv[4];
#pragma unroll
        for (int i = 0; i < 4; i++)
            bv[i] = *(const half8*)(w3o + (size_t)kb * 8192 + (size_t)(i * 256 + tid) * 8);
        __syncthreads();
        *(half8*)&As[tid >> 2][(tid & 3) * 8] = av;
#pragma unroll
        for (int i = 0; i < 4; i++) {
            int c = i * 256 + tid;
            *(half8*)&Bs[c >> 2][(c & 3) * 8] = bv[i];
        }
        __syncthreads();
        half8 af[4], bf[4];
#pragma unroll
        for (int mf = 0; mf < 4; mf++) af[mf] = *(half8*)&As[mf * 16 + lrow][lk8];
#pragma unroll
        for (int nf = 0; nf < 4; nf++) bf[nf] = *(half8*)&Bs[wave * 64 + nf * 16 + lrow][lk8];
#pragma unroll
        for (int mf = 0; mf < 4; mf++)
#pragma unroll
            for (int nf = 0; nf < 4; nf++)
                acc[mf][nf] = __builtin_amdgcn_mfma_f32_16x16x32_f16(af[mf], bf[nf], acc[mf][nf], 0, 0, 0);
    }
#pragma unroll
    for (int mf = 0; mf < 4; mf++)
#pragma unroll
        for (int nf = 0; nf < 4; nf++)
#pragma unroll
            for (int ri = 0; ri < 4; ri++) {
                int row = m0 + mf * 16 + (lane >> 4) * 4 + ri;
                int col = wave * 64 + nf * 16 + lrow;
                out[(size_t)row * 256 + col] = acc[mf][nf][ri] + bo[col];
            }
}

extern "C" void kernel_launch(void* const* d_in, const int* in_sizes, int n_in,
                              void* d_out, int out_size, void* d_ws, size_t ws_size,
                              hipStream_t stream) {
    const float* m = (const float*)d_in[0];
    const float* z = (const float*)d_in[1];
    const float* ln_m_w = (const float*)d_in[2];
    const float* ln_m_b = (const float*)d_in[3];
    const float* ln_z_w = (const float*)d_in[4];
    const float* ln_z_b = (const float*)d_in[5];
    const float* Wz = (const float*)d_in[6];
    const float* Wq = (const float*)d_in[7];
    const float* Wk = (const float*)d_in[8];
    const float* Wv = (const float*)d_in[9];
    const float* Wg = (const float*)d_in[10];
    const float* bg = (const float*)d_in[11];
    const float* Wo = (const float*)d_in[12];
    const float* bo = (const float*)d_in[13];
    float* out = (float*)d_out;

    const size_t NE = (size_t)S_DIM * R_DIM * CM_DIM;  // 8388608
    _Float16* hb = (_Float16*)d_ws;
    _Float16* mn_h = hb;
    _Float16* qh = hb + NE;
    _Float16* kh = hb + 2 * NE;
    _Float16* vh = hb + 3 * NE;
    _Float16* gh = hb + 4 * NE;
    _Float16* oh = hb + 5 * NE;
    _Float16* w3 = hb + 6 * NE;                         // 5*65536 halves
    float* bias_t = (float*)(hb + 6 * NE + 5 * 65536);  // H*R*R f32
    float* u_g = bias_t + (size_t)H_DIM * 65536;        // 8*ZPAD f32
    float* UB = u_g + 8 * ZPAD;                         // 16 f32

    hipLaunchKernelGGL(convert_w_kernel, dim3(8, 5), dim3(256), 0, stream,
                       Wq, Wk, Wv, Wg, Wo, w3);
    hipLaunchKernelGGL(prep_wz_kernel, dim3(1), dim3(64), 0, stream,
                       ln_z_w, ln_z_b, Wz, u_g, UB);
    hipLaunchKernelGGL(ln_m_kernel, dim3(S_DIM * R_DIM), dim3(64), 0, stream,
                       m, ln_m_w, ln_m_b, mn_h);
    hipLaunchKernelGGL(ln_z_bias_kernel, dim3(1024), dim3(256), 0, stream,
                       z, u_g, UB, bias_t);
    hipLaunchKernelGGL(proj_mfma_kernel, dim3(512, 4), dim3(256), 0, stream,
                       mn_h, w3, bg, qh, kh, vh, gh);
    hipLaunchKernelGGL(attn_mfma_kernel, dim3(S_DIM, H_DIM), dim3(256), 0, stream,
                       qh, kh, vh, bias_t, oh);
    hipLaunchKernelGGL(out_mfma_kernel, dim3(512), dim3(256), 0, stream,
                       gh, oh, w3 + 4 * 65536, bo, out);
}